// Round 1
// baseline (3772.308 us; speedup 1.0000x reference)
//
#include <hip/hip_runtime.h>

// ConvTranspose3d: x(2,64,32,32,32) fp32, w(64,32,3,3,3) torch layout (Cin,Cout,kD,kH,kW),
// bias(32). stride=2, pad=1, out_pad=1, dil=2, k=3 -> out (2,32,66,66,66).
//
// Gather form: out[n,co,od,oh,ow] = bias + sum_{ci,kd,kh,kw} x[n,ci,id,ih,iw]*w[ci,co,kd,kh,kw]
// with id = (od + 1 - 2*kd)/2 requiring od odd. Reference zero-pads the trailing
// output_padding plane BEFORE bias, so conv region is od,oh,ow in {1,3,...,63}
// (odd grid dp,hp,wp in [0,32), id = dp+1-kd). All other positions = bias only.

#define DOUT 66
#define CH_SZ (DOUT*DOUT*DOUT)      // 287496
#define OUT_TOTAL (2*32*CH_SZ)      // 18,399,744

__global__ void bias_fill(const float* __restrict__ bias, float4* __restrict__ out4) {
    unsigned i = blockIdx.x * 256u + threadIdx.x;
    const unsigned total4 = OUT_TOTAL / 4u;       // 4,599,936 (CH_SZ divisible by 4)
    if (i >= total4) return;
    unsigned co = (i / (CH_SZ / 4u)) & 31u;       // channel of this float4 (never straddles)
    float v = bias[co];
    out4[i] = make_float4(v, v, v, v);
}

__global__ void __launch_bounds__(256) convt_odd(const float* __restrict__ x,
                                                 const float* __restrict__ wgt,
                                                 const float* __restrict__ bias,
                                                 float* __restrict__ out) {
    // block = 256 threads = 32 co (fastest) x 8 wp
    const int co = threadIdx.x & 31;
    const int wi = threadIdx.x >> 5;            // 0..7
    unsigned b  = blockIdx.x;                   // 8192 blocks: wt(4) hp(32) dp(32) n(2)
    const int wt = b & 3;
    const int hp = (b >> 2) & 31;
    const int dp = (b >> 7) & 31;
    const int n  = b >> 12;
    const int wp = wt * 8 + wi;                 // 0..31

    float acc = 0.f;
    const float* xn = x + n * (64 * 32 * 32 * 32);

    for (int ci = 0; ci < 64; ++ci) {
        const float* xb = xn + ci * (32 * 32 * 32);
        const float* wb = wgt + (ci * 32 + co) * 27;
        #pragma unroll
        for (int kd = 0; kd < 3; ++kd) {
            const int id = dp + 1 - kd;                 // {dp+1, dp, dp-1}
            if ((unsigned)id >= 32u) continue;          // uniform per block
            #pragma unroll
            for (int kh = 0; kh < 3; ++kh) {
                const int ih = hp + 1 - kh;
                if ((unsigned)ih >= 32u) continue;      // uniform per block
                const float* xrow = xb + (id * 32 + ih) * 32;
                const float* wrow = wb + kd * 9 + kh * 3;
                #pragma unroll
                for (int kw = 0; kw < 3; ++kw) {
                    const int iw = wp + 1 - kw;
                    if ((unsigned)iw >= 32u) continue;  // diverges only at wp=0/31
                    acc += xrow[iw] * wrow[kw];
                }
            }
        }
    }

    const int od = 2 * dp + 1, oh = 2 * hp + 1, ow = 2 * wp + 1;
    out[(((n * 32 + co) * DOUT + od) * DOUT + oh) * DOUT + ow] = acc + bias[co];
}

extern "C" void kernel_launch(void* const* d_in, const int* in_sizes, int n_in,
                              void* d_out, int out_size, void* d_ws, size_t ws_size,
                              hipStream_t stream) {
    const float* x    = (const float*)d_in[0];   // 2*64*32^3
    const float* wgt  = (const float*)d_in[1];   // 64*32*27
    const float* bias = (const float*)d_in[2];   // 32
    float* out = (float*)d_out;

    const unsigned total4 = OUT_TOTAL / 4u;
    bias_fill<<<(total4 + 255) / 256, 256, 0, stream>>>(bias, (float4*)out);

    // 2 n * 32 dp * 32 hp * 4 wtiles = 8192 blocks
    convt_odd<<<8192, 256, 0, stream>>>(x, wgt, bias, out);
}

// Round 2
// 261.687 us; speedup vs baseline: 14.4154x; 14.4154x over previous
//
#include <hip/hip_runtime.h>

// ConvTranspose3d: x(2,64,32,32,32) fp32, w(64,32,3,3,3) (Cin,Cout,kD,kH,kW), bias(32).
// stride=2, pad=1, out_pad=1, dil=2 -> out (2,32,66,66,66).
// Only odd output coords get conv contributions: od=2*dp+1, dp in [0,32), id = dp+1-kd.
// Everything else = bias (bias_fill kernel). Conv kernel computes the odd grid.
//
// R2: latency-bound fix. Block = 2dp x 1hp x 32wp x 32co (1024 blocks). Thread =
// (co, wq) with 8 independent accumulators (2dp x 4wp). x staged in LDS in 8-ci
// chunks (padded rows, 16B aligned), pulled to registers as float4+float2 per row
// (broadcast across co lanes -> no bank conflicts). Weights (27 floats per ci,co)
// register-resident, L2-served.

#define DOUT 66
#define CH_SZ (DOUT*DOUT*DOUT)      // 287496
#define OUT_TOTAL (2*32*CH_SZ)      // 18,399,744

__global__ void bias_fill(const float* __restrict__ bias, float4* __restrict__ out4) {
    unsigned i = blockIdx.x * 256u + threadIdx.x;
    const unsigned total4 = OUT_TOTAL / 4u;
    if (i >= total4) return;
    unsigned co = (i / (CH_SZ / 4u)) & 31u;
    float v = bias[co];
    out4[i] = make_float4(v, v, v, v);
}

// xlds row stride 36 floats = 144B (16B multiple) -> aligned float4/float2 reads.
__global__ void __launch_bounds__(256, 3) convt_odd(const float* __restrict__ x,
                                                    const float* __restrict__ wgt,
                                                    const float* __restrict__ bias,
                                                    float* __restrict__ out) {
    __shared__ __align__(16) float xlds[8][4][3][36];   // ci, id(4), ih(3), iw(34 pad 36)

    const int tid = threadIdx.x;
    const int co = tid & 31;
    const int wq = tid >> 5;            // 0..7 -> wp = wq*4 + ws

    const unsigned b = blockIdx.x;      // 1024 blocks: hp(32), dpt(16), n(2)
    const int hp  = b & 31;
    const int dp0 = ((b >> 5) & 15) * 2;
    const int n   = b >> 9;

    float acc[2][4];
    #pragma unroll
    for (int d = 0; d < 2; ++d)
        #pragma unroll
        for (int ws = 0; ws < 4; ++ws) acc[d][ws] = 0.f;

    const float* xn = x + n * (64 * 32768);

    for (int ci0 = 0; ci0 < 64; ci0 += 8) {
        __syncthreads();
        // stage 8 ci x 4 id x 3 ih x 34 iw (zero halo)
        for (int idx = tid; idx < 8 * 408; idx += 256) {
            int c   = idx / 408;
            int r   = idx - c * 408;
            int idp = r / 102;          // 3*34
            int r2  = r - idp * 102;
            int ihp = r2 / 34;
            int iwp = r2 - ihp * 34;
            int id = dp0 - 1 + idp;
            int ih = hp - 1 + ihp;
            int iw = iwp - 1;
            float v = 0.f;
            if ((unsigned)id < 32u && (unsigned)ih < 32u && (unsigned)iw < 32u)
                v = xn[(ci0 + c) * 32768 + (id * 32 + ih) * 32 + iw];
            xlds[c][idp][ihp][iwp] = v;
        }
        __syncthreads();

        for (int c = 0; c < 8; ++c) {
            // weights for (ci0+c, co): 27 contiguous floats, L2-resident
            float wr[27];
            const float* wg = wgt + ((ci0 + c) * 32 + co) * 27;
            #pragma unroll
            for (int t = 0; t < 27; ++t) wr[t] = wg[t];

            // pull 12 rows x 6 floats from LDS (broadcast across co lanes)
            float xr[12][6];
            #pragma unroll
            for (int idl = 0; idl < 4; ++idl)
                #pragma unroll
                for (int ihl = 0; ihl < 3; ++ihl) {
                    const float* row = &xlds[c][idl][ihl][wq * 4];
                    float4 v4 = *(const float4*)row;
                    float2 v2 = *(const float2*)(row + 4);
                    float* xd = xr[idl * 3 + ihl];
                    xd[0] = v4.x; xd[1] = v4.y; xd[2] = v4.z; xd[3] = v4.w;
                    xd[4] = v2.x; xd[5] = v2.y;
                }

            #pragma unroll
            for (int kd = 0; kd < 3; ++kd)
                #pragma unroll
                for (int kh = 0; kh < 3; ++kh) {
                    const int ihl = 2 - kh;
                    #pragma unroll
                    for (int kw = 0; kw < 3; ++kw) {
                        const float wv = wr[kd * 9 + kh * 3 + kw];
                        #pragma unroll
                        for (int d = 0; d < 2; ++d) {
                            const int idl = d + 2 - kd;
                            const float* xrow = xr[idl * 3 + ihl];
                            #pragma unroll
                            for (int ws = 0; ws < 4; ++ws)
                                acc[d][ws] = fmaf(xrow[ws + 2 - kw], wv, acc[d][ws]);
                        }
                    }
                }
        }
    }

    const float bv = bias[co];
    const int oh = 2 * hp + 1;
    #pragma unroll
    for (int d = 0; d < 2; ++d) {
        const int od = 2 * (dp0 + d) + 1;
        float* orow = out + (((n * 32 + co) * DOUT + od) * DOUT + oh) * DOUT + 1;
        #pragma unroll
        for (int ws = 0; ws < 4; ++ws) {
            const int wp = wq * 4 + ws;
            orow[2 * wp] = acc[d][ws] + bv;
        }
    }
}

extern "C" void kernel_launch(void* const* d_in, const int* in_sizes, int n_in,
                              void* d_out, int out_size, void* d_ws, size_t ws_size,
                              hipStream_t stream) {
    const float* x    = (const float*)d_in[0];
    const float* wgt  = (const float*)d_in[1];
    const float* bias = (const float*)d_in[2];
    float* out = (float*)d_out;

    const unsigned total4 = OUT_TOTAL / 4u;
    bias_fill<<<(total4 + 255) / 256, 256, 0, stream>>>(bias, (float4*)out);
    convt_odd<<<1024, 256, 0, stream>>>(x, wgt, bias, out);
}

// Round 4
// 143.722 us; speedup vs baseline: 26.2472x; 1.8208x over previous
//
#include <hip/hip_runtime.h>

// ConvTranspose3d (2,64,32^3) fp32 -> (2,32,66^3), stride2 pad1 outpad1 dil2 k3.
// Odd-grid MFMA formulation: out[n,co,2dp+1,2hp+1,2wp+1] = bias[co] +
//   sum_{ci,kd,kh,kw} x[n,ci,dp+1-kd,hp+1-kh,wp+1-kw] * w[ci,co,kd,kh,kw]
// == GEMM M=co(32) x K=ci*tap(1728) x N=pos(65536) via v_mfma_f32_32x32x16_f16.
// Everything else in the output is pure bias.

#define DOUT 66
#define CH_SZ (DOUT*DOUT*DOUT)          // 287496
#define NROWS (2*32*DOUT*DOUT)          // 278784 rows of 66 floats

typedef _Float16 half8  __attribute__((ext_vector_type(8)));
typedef float    floatx16 __attribute__((ext_vector_type(16)));

// ---- k0: w (64,32,3,3,3) f32 -> wT[tap(27)][co(32)][ci(64)] f16 in d_ws ----
__global__ void w_transpose(const float* __restrict__ w, _Float16* __restrict__ wT) {
    int o = blockIdx.x * 256 + threadIdx.x;          // o = tap*2048 + co*64 + ci
    if (o >= 27 * 32 * 64) return;
    int ci = o & 63, co = (o >> 6) & 31, tap = o >> 11;
    wT[o] = (_Float16)w[ci * (32 * 27) + co * 27 + tap];
}

// ---- k1: bias everywhere except the odd/odd conv rows (od,oh odd, <65) ----
__global__ void bias_rows(const float* __restrict__ bias, float* __restrict__ out) {
    unsigned g = blockIdx.x * 256u + threadIdx.x;    // g = row*33 + slot
    unsigned row = g / 33u, slot = g - row * 33u;
    if (row >= NROWS) return;
    unsigned oh = row % 66u;
    unsigned r2 = row / 66u;
    unsigned od = r2 % 66u;
    unsigned co = (r2 / 66u) & 31u;
    if ((od & 1u) && (oh & 1u) && od < 65u && oh < 65u) return;  // conv-owned row
    float v = bias[co];
    float2* p = (float2*)(out + (size_t)row * 66u);  // row base = 264B, 8B aligned
    p[slot] = make_float2(v, v);
}

// ---- k2: MFMA conv over the odd grid ----
// block = 256 thr (4 waves). Block tile: (n, dp, 4 hp rows), wave = one hp row
// (32 wp x 32 co). LDS: x[18 rows][34 iw][64 ci] f16 with 16B-granule XOR swizzle.
__global__ void __launch_bounds__(256, 2) convt_mfma(
    const float* __restrict__ x, const _Float16* __restrict__ wT,
    const float* __restrict__ bias, float* __restrict__ out)
{
    __shared__ unsigned int xlds[18 * 34 * 32];      // 78336 B (u32 = 2 f16 ci-pair)

    const int tid  = threadIdx.x;
    const int lane = tid & 63;
    const int wv   = tid >> 6;                       // wave 0..3 -> hp row

    // XCD-slab block swizzle: per XCD: fixed n, hpt pair, all dp (x slab ~2.6MB ~ L2)
    unsigned b   = blockIdx.x;                       // 512 blocks
    unsigned xcd = b & 7u, li = b >> 3;              // li 0..63
    const int dp  = li & 31;
    const int q   = li >> 5;                         // 0..1
    const int n   = xcd & 1;
    const int hpt = ((xcd >> 1) << 1) + q;           // 0..7
    const int hpb = hpt * 4;

    // ---------------- stage x tile: 64ci x 3id x 6ih x 34iw (zero halo) -------
    const float* xn = x + (size_t)n * 64 * 32768;
    const int l32 = tid & 31;                        // iw lane
    const int grp = tid >> 5;                        // 0..7 -> ci-pair group

    #pragma unroll
    for (int idl = 0; idl < 3; ++idl) {
        const int id = dp - 1 + idl;
        const bool idv = (unsigned)id < 32u;
        #pragma unroll
        for (int ihl = 0; ihl < 6; ++ihl) {
            const int ih = hpb - 1 + ihl;
            const bool rv = idv && ((unsigned)ih < 32u);
            const int row = idl * 6 + ihl;
            const float* xr = xn + ((id * 32 + ih) * 32);
            // main: iwl = l32 (iw = l32-1), pairs p = grp + 8k
            #pragma unroll
            for (int k = 0; k < 4; ++k) {
                const int p = grp + 8 * k;           // ci pair 0..31
                const int c0 = 2 * p;
                float a = 0.f, bb = 0.f;
                const int iw = l32 - 1;
                if (rv && iw >= 0) {                 // iw <= 30 here, always < 32
                    a  = xr[(size_t)c0 * 32768 + iw];
                    bb = xr[(size_t)(c0 + 1) * 32768 + iw];
                }
                auto pk = __builtin_amdgcn_cvt_pkrtz(a, bb);
                const int sp = row * 34 + l32;
                const int gsw = (p >> 2) ^ (sp & 7);
                xlds[sp * 32 + gsw * 4 + (p & 3)] = __builtin_bit_cast(unsigned int, pk);
            }
            // tail: iwl = 32 (iw=31, valid) and iwl = 33 (iw=32, zero)
            if (l32 < 2) {
                const int iwl = 32 + l32;
                const int iw = iwl - 1;
                const bool v = rv && iw < 32;
                #pragma unroll
                for (int k = 0; k < 4; ++k) {
                    const int p = grp + 8 * k;
                    const int c0 = 2 * p;
                    float a = 0.f, bb = 0.f;
                    if (v) {
                        a  = xr[(size_t)c0 * 32768 + iw];
                        bb = xr[(size_t)(c0 + 1) * 32768 + iw];
                    }
                    auto pk = __builtin_amdgcn_cvt_pkrtz(a, bb);
                    const int sp = row * 34 + iwl;
                    const int gsw = (p >> 2) ^ (sp & 7);
                    xlds[sp * 32 + gsw * 4 + (p & 3)] = __builtin_bit_cast(unsigned int, pk);
                }
            }
        }
    }
    __syncthreads();

    // ---------------- MFMA K-loop: 27 taps x 4 ci-chunks ----------------------
    floatx16 acc = {};
    const int wp    = lane & 31;                     // B free dim / D col
    const int khalf = lane >> 5;                     // k half
    // A-frag lane base in wT halves: co = lane&31 rows
    const _Float16* wtl = wT + (lane & 31) * 64 + khalf * 8;

    #pragma unroll
    for (int kd = 0; kd < 3; ++kd) {
        const int idl = 2 - kd;
        #pragma unroll
        for (int kh = 0; kh < 3; ++kh) {
            const int row = idl * 6 + (wv + 2 - kh);
            #pragma unroll
            for (int kw = 0; kw < 3; ++kw) {
                const int iwl = wp + 2 - kw;
                const int sp = row * 34 + iwl;
                const int sp7 = sp & 7;
                const int tap = (kd * 3 + kh) * 3 + kw;
                const unsigned int* xrow = xlds + sp * 32;
                #pragma unroll
                for (int cc = 0; cc < 4; ++cc) {
                    const int g = cc * 2 + khalf;
                    uint4 bu = *(const uint4*)(xrow + ((g ^ sp7) * 4));
                    uint4 au = *(const uint4*)(wtl + tap * 2048 + cc * 16);
                    acc = __builtin_amdgcn_mfma_f32_32x32x16_f16(
                        __builtin_bit_cast(half8, au),
                        __builtin_bit_cast(half8, bu), acc, 0, 0, 0);
                }
            }
        }
    }

    // ---------------- store: full odd/odd rows (evens + tail = bias) ----------
    const int od = 2 * dp + 1;
    const int oh = 2 * (hpb + wv) + 1;
    #pragma unroll
    for (int r = 0; r < 16; ++r) {
        const int co = (r & 3) + 8 * (r >> 2) + 4 * khalf;   // verified C/D row map
        const float bv = bias[co];
        float* orow = out + (size_t)(((n * 32 + co) * DOUT + od) * DOUT + oh) * DOUT;
        ((float2*)orow)[wp] = make_float2(bv, acc[r] + bv);  // ow = 2wp, 2wp+1
        if (wp == 31) ((float2*)orow)[32] = make_float2(bv, bv);  // ow = 64, 65
    }
}

extern "C" void kernel_launch(void* const* d_in, const int* in_sizes, int n_in,
                              void* d_out, int out_size, void* d_ws, size_t ws_size,
                              hipStream_t stream) {
    const float* x    = (const float*)d_in[0];
    const float* wgt  = (const float*)d_in[1];
    const float* bias = (const float*)d_in[2];
    float* out = (float*)d_out;
    _Float16* wT = (_Float16*)d_ws;                  // 110,592 B of scratch

    w_transpose<<<216, 256, 0, stream>>>(wgt, wT);
    bias_rows<<<(NROWS * 33 + 255) / 256, 256, 0, stream>>>(bias, out);
    convt_mfma<<<512, 256, 0, stream>>>(x, wT, bias, out);
}

// Round 5
// 130.586 us; speedup vs baseline: 28.8874x; 1.1006x over previous
//
#include <hip/hip_runtime.h>

// ConvTranspose3d (2,64,32^3) fp32 -> (2,32,66^3), stride2 pad1 outpad1 dil2 k3.
// Odd-grid MFMA: out[n,co,2dp+1,2hp+1,2wp+1] = bias[co] +
//   sum_{ci,kd,kh,kw} x[n,ci,dp+1-kd,hp+1-kh,wp+1-kw] * w[ci,co,kd,kh,kw]
// GEMM M=co(32) K=ci(64)*tap(27) N=pos(65536) via v_mfma_f32_32x32x16_f16.
// All non-odd positions = bias (bias_fill covers everything; conv overwrites).

#define DOUT 66
#define CH_SZ (DOUT*DOUT*DOUT)          // 287496
#define TOTAL4 (2*32*CH_SZ/4)           // 4,599,936 float4s in out

typedef _Float16 half8 __attribute__((ext_vector_type(8)));
typedef float    floatx16 __attribute__((ext_vector_type(16)));

// ---- k0: w (64,32,3,3,3) f32 -> wT[tap(27)][co(32)][ci(64)] f16 in d_ws ----
__global__ void w_transpose(const float* __restrict__ w, _Float16* __restrict__ wT) {
    int o = blockIdx.x * 256 + threadIdx.x;          // o = tap*2048 + co*64 + ci
    if (o >= 27 * 32 * 64) return;
    int ci = o & 63, co = (o >> 6) & 31, tap = o >> 11;
    wT[o] = (_Float16)w[ci * (32 * 27) + co * 27 + tap];
}

// ---- k1: bias over the ENTIRE output, fat threads (16 float4 each) ----
__global__ void bias_fill(const float* __restrict__ bias, float4* __restrict__ out4) {
    const int tid = threadIdx.x;
    const unsigned base = blockIdx.x * 4096u;
    #pragma unroll
    for (int j = 0; j < 16; ++j) {
        unsigned idx = base + j * 256u + tid;
        if (idx < TOTAL4) {
            unsigned co = (idx / 71874u) & 31u;      // 71874 = CH_SZ/4
            float v = bias[co];
            out4[idx] = make_float4(v, v, v, v);
        }
    }
}

// ---- k2: MFMA conv over the odd grid ----
// block = 256 thr (4 waves), tile (n, dp, 4 hp rows); wave = 32wp x 32co.
// LDS x[18 sp-rows][34 iwl][32 u32 ci-pairs], granule-XOR swizzled:
//   u32 slot of pair p at row sp = ((p>>2) ^ (sp&7))*4 + (p&3).
__global__ void __launch_bounds__(256, 2) convt_mfma(
    const float* __restrict__ x, const _Float16* __restrict__ wT,
    const float* __restrict__ bias, float* __restrict__ out)
{
    __shared__ unsigned int xlds[18 * 34 * 32];      // 78336 B

    const int tid  = threadIdx.x;
    const int lane = tid & 63;
    const int wv   = tid >> 6;                       // wave -> hp row

    unsigned b   = blockIdx.x;                       // 512 blocks
    unsigned xcd = b & 7u, li = b >> 3;
    const int dp  = li & 31;
    const int q   = li >> 5;
    const int n   = xcd & 1;
    const int hpt = ((xcd >> 1) << 1) + q;
    const int hpb = hpt * 4;

    // zero halo columns iwl = 0 and 33 (18 rows x 2 x 32 u32), conflict-free
    for (int i = tid; i < 1152; i += 256) {
        int row = i >> 6, rem = i & 63;
        int iwl = (rem >> 5) * 33, slot = rem & 31;
        xlds[(row * 34 + iwl) * 32 + slot] = 0;
    }

    // ---- staging: lanes = 32 iw (fast) x 8 ci-octets ----
    // thread: 8 coalesced dword loads (planes 8G..8G+7) -> 4 cvt_pkrtz -> 1 b128
    const float* xn = x + (size_t)n * (64 * 32768);
    const int l32 = tid & 31;                        // iw = l32, iwl = l32+1
    const int G   = tid >> 5;                        // ci octet 0..7
    const float* xg = xn + (size_t)(8 * G) * 32768 + l32;

    #pragma unroll
    for (int idl = 0; idl < 3; ++idl) {
        const int id = dp - 1 + idl;
        const bool idv = (unsigned)id < 32u;
        #pragma unroll
        for (int ihl = 0; ihl < 6; ++ihl) {
            const int ih = hpb - 1 + ihl;
            const bool rv = idv && ((unsigned)ih < 32u);   // block-uniform
            const int row = idl * 6 + ihl;
            float f[8] = {0.f, 0.f, 0.f, 0.f, 0.f, 0.f, 0.f, 0.f};
            if (rv) {
                const float* xr = xg + (id * 32 + ih) * 32;
                #pragma unroll
                for (int j = 0; j < 8; ++j) f[j] = xr[(size_t)j * 32768];
            }
            uint4 pk;
            pk.x = __builtin_bit_cast(unsigned int, __builtin_amdgcn_cvt_pkrtz(f[0], f[1]));
            pk.y = __builtin_bit_cast(unsigned int, __builtin_amdgcn_cvt_pkrtz(f[2], f[3]));
            pk.z = __builtin_bit_cast(unsigned int, __builtin_amdgcn_cvt_pkrtz(f[4], f[5]));
            pk.w = __builtin_bit_cast(unsigned int, __builtin_amdgcn_cvt_pkrtz(f[6], f[7]));
            const int sp = row * 34 + (l32 + 1);
            *(uint4*)&xlds[sp * 32 + ((G ^ (sp & 7)) << 2)] = pk;
        }
    }
    __syncthreads();

    // ---- MFMA K-loop: cc-outer (k chunks of 16 ci), tap-inner (27) ----
    const int wp    = lane & 31;
    const int khalf = lane >> 5;
    const _Float16* wtl = wT + (lane & 31) * 64 + khalf * 8;

    floatx16 acc = {};
    #pragma unroll 1
    for (int cc = 0; cc < 4; ++cc) {
        uint4 a[27];                                  // 27 independent, batched
        const _Float16* wcc = wtl + cc * 16;
        #pragma unroll
        for (int t = 0; t < 27; ++t)
            a[t] = *(const uint4*)(wcc + t * 2048);

        const int g = cc * 2 + khalf;
        #pragma unroll
        for (int kd = 0; kd < 3; ++kd) {
            const int idl = 2 - kd;
            #pragma unroll
            for (int kh = 0; kh < 3; ++kh) {
                const int row = idl * 6 + (wv + 2 - kh);
                #pragma unroll
                for (int kw = 0; kw < 3; ++kw) {
                    const int sp = row * 34 + (wp + 2 - kw);
                    const uint4* bp = (const uint4*)&xlds[sp * 32 + ((g ^ (sp & 7)) << 2)];
                    const int tap = (kd * 3 + kh) * 3 + kw;
                    acc = __builtin_amdgcn_mfma_f32_32x32x16_f16(
                        __builtin_bit_cast(half8, a[tap]),
                        __builtin_bit_cast(half8, *bp), acc, 0, 0, 0);
                }
            }
        }
    }

    // ---- store full odd/odd rows (C/D map verified in R4) ----
    const int od = 2 * dp + 1;
    const int oh = 2 * (hpb + wv) + 1;
    #pragma unroll
    for (int r = 0; r < 16; ++r) {
        const int co = (r & 3) + 8 * (r >> 2) + 4 * khalf;
        const float bv = bias[co];
        float* orow = out + (size_t)(((n * 32 + co) * DOUT + od) * DOUT + oh) * DOUT;
        ((float2*)orow)[wp] = make_float2(bv, acc[r] + bv);
        if (wp == 31) ((float2*)orow)[32] = make_float2(bv, bv);
    }
}

extern "C" void kernel_launch(void* const* d_in, const int* in_sizes, int n_in,
                              void* d_out, int out_size, void* d_ws, size_t ws_size,
                              hipStream_t stream) {
    const float* x    = (const float*)d_in[0];
    const float* wgt  = (const float*)d_in[1];
    const float* bias = (const float*)d_in[2];
    float* out = (float*)d_out;
    _Float16* wT = (_Float16*)d_ws;                  // 110,592 B scratch

    w_transpose<<<216, 256, 0, stream>>>(wgt, wT);
    bias_fill<<<(TOTAL4 + 4095) / 4096, 256, 0, stream>>>(bias, (float4*)out);
    convt_mfma<<<512, 256, 0, stream>>>(x, wT, bias, out);
}

// Round 6
// 126.199 us; speedup vs baseline: 29.8917x; 1.0348x over previous
//
#include <hip/hip_runtime.h>

// ConvTranspose3d (2,64,32^3) fp32 -> (2,32,66^3), stride2 pad1 outpad1 dil2 k3.
// Odd-grid MFMA: out[n,co,2dp+1,2hp+1,2wp+1] = bias[co] +
//   sum_{ci,kd,kh,kw} x[n,ci,dp+1-kd,hp+1-kh,wp+1-kw] * w[ci,co,kd,kh,kw]
// GEMM M=co(32) K=ci(64)*tap(27) N=pos(65536) via v_mfma_f32_32x32x16_f16.
// Conv blocks write FULL odd-od planes (conv on odd oh rows, bias on the rest);
// bias_planes covers the 34 pure-bias planes (od even, od=65). Each output
// byte is written exactly once (73.6 MB total).

#define DOUT 66
#define CH_SZ (DOUT*DOUT*DOUT)          // 287496
#define PL    (DOUT*DOUT)               // 4356 floats per plane

typedef _Float16 half8 __attribute__((ext_vector_type(8)));
typedef float    floatx16 __attribute__((ext_vector_type(16)));

// ---- k0: w (64,32,3,3,3) f32 -> wT[tap(27)][co(32)][ci(64)] f16 in d_ws ----
__global__ void w_transpose(const float* __restrict__ w, _Float16* __restrict__ wT) {
    int o = blockIdx.x * 256 + threadIdx.x;          // o = tap*2048 + co*64 + ci
    if (o >= 27 * 32 * 64) return;
    int ci = o & 63, co = (o >> 6) & 31, tap = o >> 11;
    wT[o] = (_Float16)w[ci * (32 * 27) + co * 27 + tap];
}

// ---- k1: bias over the 34 pure-bias planes per (n,co): od even (33) + od=65 ----
#define BIAS_TOT4 (2*32*34*(PL/4))      // 2,369,952 float4s (PL=4356 -> 1089 f4/plane)
__global__ void bias_planes(const float* __restrict__ bias, float4* __restrict__ out4_unused,
                            float* __restrict__ out) {
    const int tid = threadIdx.x;
    const unsigned base = blockIdx.x * 4096u;
    #pragma unroll
    for (int j = 0; j < 16; ++j) {
        unsigned idx = base + j * 256u + tid;
        if (idx >= BIAS_TOT4) continue;
        unsigned pl = idx / 1089u;                   // which (n,co,e) plane
        unsigned slot = idx - pl * 1089u;
        unsigned e  = pl % 34u;                      // 0..32 -> od=2e, 33 -> od=65
        unsigned nc = pl / 34u;                      // n*32+co
        unsigned od = (e < 33u) ? 2u * e : 65u;
        float v = bias[nc & 31u];
        float4* p = (float4*)(out + ((size_t)nc * DOUT + od) * PL);
        p[slot] = make_float4(v, v, v, v);
    }
}

// ---- k2: MFMA conv over the odd grid; writes full odd-od planes ----
// block = 256 thr (4 waves), tile (n, dp, 4 hp rows); wave = 32wp x 32co.
// LDS x[18 sp-rows][34 iwl][32 u32 ci-pairs], granule-XOR swizzle:
//   u32 slot of ci-pair p at row sp = ((p>>2) ^ (sp&7))*4 + (p&3).
__global__ void __launch_bounds__(256, 2) convt_mfma(
    const float* __restrict__ x, const _Float16* __restrict__ wT,
    const float* __restrict__ bias, float* __restrict__ out)
{
    __shared__ unsigned int xlds[18 * 34 * 32];      // 78336 B

    const int tid  = threadIdx.x;
    const int lane = tid & 63;
    const int wv   = tid >> 6;                       // wave -> hp row

    unsigned b   = blockIdx.x;                       // 512 blocks
    unsigned xcd = b & 7u, li = b >> 3;
    const int dp  = li & 31;
    const int q   = li >> 5;
    const int n   = xcd & 1;
    const int hpt = ((xcd >> 1) << 1) + q;           // 0..7
    const int hpb = hpt * 4;

    // zero halo columns iwl = 0 and 33
    for (int i = tid; i < 1152; i += 256) {
        int row = i >> 6, rem = i & 63;
        int iwl = (rem >> 5) * 33, slot = rem & 31;
        xlds[(row * 34 + iwl) * 32 + slot] = 0;
    }

    // ---- staging: lanes = 32 iw x 8 ci-octets; 8 coalesced loads -> 1 b128 ----
    const float* xn = x + (size_t)n * (64 * 32768);
    const int l32 = tid & 31;                        // iw = l32, iwl = l32+1
    const int G   = tid >> 5;                        // ci octet
    const float* xg = xn + (size_t)(8 * G) * 32768 + l32;

    #pragma unroll
    for (int idl = 0; idl < 3; ++idl) {
        const int id = dp - 1 + idl;
        const bool idv = (unsigned)id < 32u;
        #pragma unroll
        for (int ihl = 0; ihl < 6; ++ihl) {
            const int ih = hpb - 1 + ihl;
            const bool rv = idv && ((unsigned)ih < 32u);   // block-uniform
            const int row = idl * 6 + ihl;
            float f[8] = {0.f, 0.f, 0.f, 0.f, 0.f, 0.f, 0.f, 0.f};
            if (rv) {
                const float* xr = xg + (id * 32 + ih) * 32;
                #pragma unroll
                for (int j = 0; j < 8; ++j) f[j] = xr[(size_t)j * 32768];
            }
            uint4 pk;
            pk.x = __builtin_bit_cast(unsigned int, __builtin_amdgcn_cvt_pkrtz(f[0], f[1]));
            pk.y = __builtin_bit_cast(unsigned int, __builtin_amdgcn_cvt_pkrtz(f[2], f[3]));
            pk.z = __builtin_bit_cast(unsigned int, __builtin_amdgcn_cvt_pkrtz(f[4], f[5]));
            pk.w = __builtin_bit_cast(unsigned int, __builtin_amdgcn_cvt_pkrtz(f[6], f[7]));
            const int sp = row * 34 + (l32 + 1);
            *(uint4*)&xlds[sp * 32 + ((G ^ (sp & 7)) << 2)] = pk;
        }
    }
    __syncthreads();

    // ---- K-loop: 9 uniform (kd,kh) iterations; inner 3 kw x 4 cc unrolled ----
    // Live set ~ 12 a + 12 b + 16 acc: no scratch spill (R5's a[27] spilled).
    const int wp    = lane & 31;
    const int khalf = lane >> 5;
    const _Float16* wbase = wT + (lane & 31) * 64 + khalf * 8;

    floatx16 acc = {};
    #pragma unroll 1
    for (int t9 = 0; t9 < 9; ++t9) {
        const int kd = t9 / 3, kh = t9 - 3 * kd;
        const int row = (2 - kd) * 6 + (wv + 2 - kh);
        #pragma unroll
        for (int kw = 0; kw < 3; ++kw) {
            const int sp  = row * 34 + (wp + 2 - kw);
            const int sp7 = sp & 7;
            const unsigned int* xrow = xlds + sp * 32;
            const _Float16* wt = wbase + (t9 * 3 + kw) * 2048;
            #pragma unroll
            for (int cc = 0; cc < 4; ++cc) {
                const int g = cc * 2 + khalf;
                uint4 bu = *(const uint4*)(xrow + ((g ^ sp7) << 2));
                uint4 au = *(const uint4*)(wt + cc * 16);
                acc = __builtin_amdgcn_mfma_f32_32x32x16_f16(
                    __builtin_bit_cast(half8, au),
                    __builtin_bit_cast(half8, bu), acc, 0, 0, 0);
            }
        }
    }

    // ---- stores: full odd-od plane coverage for this block's 4 hp ----
    const int od = 2 * dp + 1;
    const int hp = hpb + wv;
    const int oh_odd = 2 * hp + 1, oh_even = 2 * hp;
    const bool tailrows = (hpt == 7) && (wv == 3);
    #pragma unroll
    for (int r = 0; r < 16; ++r) {
        const int co = (r & 3) + 8 * (r >> 2) + 4 * khalf;   // verified C/D map
        const float bv = bias[co];
        float* pbase = out + ((size_t)(n * 32 + co) * DOUT + od) * PL;
        float2* orow = (float2*)(pbase + oh_odd * DOUT);
        float2* erow = (float2*)(pbase + oh_even * DOUT);
        orow[wp] = make_float2(bv, acc[r] + bv);
        erow[wp] = make_float2(bv, bv);
        if (wp == 31) {
            orow[32] = make_float2(bv, bv);
            erow[32] = make_float2(bv, bv);
        }
        if (tailrows) {                              // oh = 64, 65 of this plane
            float2* t0 = (float2*)(pbase + 64 * DOUT);
            float2* t1 = (float2*)(pbase + 65 * DOUT);
            t0[wp] = make_float2(bv, bv);
            t1[wp] = make_float2(bv, bv);
            if (wp == 31) { t0[32] = make_float2(bv, bv); t1[32] = make_float2(bv, bv); }
        }
    }
}

extern "C" void kernel_launch(void* const* d_in, const int* in_sizes, int n_in,
                              void* d_out, int out_size, void* d_ws, size_t ws_size,
                              hipStream_t stream) {
    const float* x    = (const float*)d_in[0];
    const float* wgt  = (const float*)d_in[1];
    const float* bias = (const float*)d_in[2];
    float* out = (float*)d_out;
    _Float16* wT = (_Float16*)d_ws;                  // 110,592 B scratch

    w_transpose<<<216, 256, 0, stream>>>(wgt, wT);
    bias_planes<<<(BIAS_TOT4 + 4095) / 4096, 256, 0, stream>>>(bias, nullptr, out);
    convt_mfma<<<512, 256, 0, stream>>>(x, wT, bias, out);
}

// Round 7
// 122.616 us; speedup vs baseline: 30.7653x; 1.0292x over previous
//
#include <hip/hip_runtime.h>

// ConvTranspose3d (2,64,32^3) fp32 -> (2,32,66^3), stride2 pad1 outpad1 dil2 k3.
// Odd-grid MFMA: out[n,co,2dp+1,2hp+1,2wp+1] = bias[co] +
//   sum_{ci,kd,kh,kw} x[n,ci,dp+1-kd,hp+1-kh,wp+1-kw] * w[ci,co,kd,kh,kw]
// GEMM M=co(32) K=ci(64)*tap(27) N=pos(65536) via v_mfma_f32_32x32x16_f16.
// R7: fat waves — each wave computes 2 hp rows (2 acc chains, A-frags reused),
// block = 4 waves = 8 hp rows, 256 blocks (1/CU), x-tile 30 sp-rows (130 KB
// dynamic LDS). Conv writes full odd-od planes; bias_planes covers even-od.

#define DOUT 66
#define PL    (DOUT*DOUT)               // 4356 floats per plane

typedef _Float16 half8 __attribute__((ext_vector_type(8)));
typedef float    floatx16 __attribute__((ext_vector_type(16)));

#define CONV_LDS_BYTES (30*34*32*4)     // 130,560 B

// ---- k0: w (64,32,3,3,3) f32 -> wT[tap(27)][co(32)][ci(64)] f16 in d_ws ----
__global__ void w_transpose(const float* __restrict__ w, _Float16* __restrict__ wT) {
    int o = blockIdx.x * 256 + threadIdx.x;          // o = tap*2048 + co*64 + ci
    if (o >= 27 * 32 * 64) return;
    int ci = o & 63, co = (o >> 6) & 31, tap = o >> 11;
    wT[o] = (_Float16)w[ci * (32 * 27) + co * 27 + tap];
}

// ---- k1: bias over the 34 pure-bias planes per (n,co): od even (33) + od=65 ----
#define BIAS_TOT4 (2*32*34*(PL/4))      // 2,369,952 float4s (1089 f4/plane)
__global__ void bias_planes(const float* __restrict__ bias, float* __restrict__ out) {
    const int tid = threadIdx.x;
    const unsigned base = blockIdx.x * 4096u;
    #pragma unroll
    for (int j = 0; j < 16; ++j) {
        unsigned idx = base + j * 256u + tid;
        if (idx >= BIAS_TOT4) continue;
        unsigned pl = idx / 1089u;
        unsigned slot = idx - pl * 1089u;
        unsigned e  = pl % 34u;                      // 0..32 -> od=2e, 33 -> od=65
        unsigned nc = pl / 34u;                      // n*32+co
        unsigned od = (e < 33u) ? 2u * e : 65u;
        float v = bias[nc & 31u];
        float4* p = (float4*)(out + ((size_t)nc * DOUT + od) * PL);
        p[slot] = make_float4(v, v, v, v);
    }
}

// ---- k2: MFMA conv; block = (n, dp, 8 hp rows), wave = 2 hp tiles ----
// LDS x[30 sp-rows (3id x 10ihl)][34 iwl][32 u32 ci-pairs], granule-XOR swizzle:
//   uint4 granule of ci-octet G at row sp sits at slot (G ^ (sp&7)).
__global__ void __launch_bounds__(256, 1) convt_mfma(
    const float* __restrict__ x, const _Float16* __restrict__ wT,
    const float* __restrict__ bias, float* __restrict__ out)
{
    extern __shared__ unsigned int xlds[];           // 30*34*32 u32 = 130,560 B

    const int tid  = threadIdx.x;
    const int lane = tid & 63;
    const int wv   = tid >> 6;                       // wave 0..3

    unsigned b   = blockIdx.x;                       // 256 blocks
    unsigned xcd = b & 7u;
    const int n   = xcd & 1;
    const int hpg = xcd >> 1;                        // 0..3
    const int dp  = b >> 3;                          // 0..31
    const int hpb = hpg * 8;

    // zero halo columns iwl = 0 and 33 (30 rows x 2 x 32 u32)
    for (int i = tid; i < 1920; i += 256) {
        int row = i >> 6, rem = i & 63;
        int iwl = (rem >> 5) * 33, slot = rem & 31;
        xlds[(row * 34 + iwl) * 32 + slot] = 0;
    }

    // ---- staging: lanes = 32 iw x 8 ci-octets; 8 coalesced loads -> 1 b128 ----
    const float* xn = x + (size_t)n * (64 * 32768);
    const int l32 = tid & 31;                        // iw = l32, iwl = l32+1
    const int G   = tid >> 5;                        // ci octet
    const float* xg = xn + (size_t)(8 * G) * 32768 + l32;

    #pragma unroll
    for (int idl = 0; idl < 3; ++idl) {
        const int id = dp - 1 + idl;
        const bool idv = (unsigned)id < 32u;
        #pragma unroll
        for (int ihl = 0; ihl < 10; ++ihl) {
            const int ih = hpb - 1 + ihl;
            const bool rv = idv && ((unsigned)ih < 32u);   // block-uniform
            const int row = idl * 10 + ihl;
            float f[8] = {0.f, 0.f, 0.f, 0.f, 0.f, 0.f, 0.f, 0.f};
            if (rv) {
                const float* xr = xg + (id * 32 + ih) * 32;
                #pragma unroll
                for (int j = 0; j < 8; ++j) f[j] = xr[(size_t)j * 32768];
            }
            uint4 pk;
            pk.x = __builtin_bit_cast(unsigned int, __builtin_amdgcn_cvt_pkrtz(f[0], f[1]));
            pk.y = __builtin_bit_cast(unsigned int, __builtin_amdgcn_cvt_pkrtz(f[2], f[3]));
            pk.z = __builtin_bit_cast(unsigned int, __builtin_amdgcn_cvt_pkrtz(f[4], f[5]));
            pk.w = __builtin_bit_cast(unsigned int, __builtin_amdgcn_cvt_pkrtz(f[6], f[7]));
            const int sp = row * 34 + (l32 + 1);
            *(uint4*)&xlds[sp * 32 + ((G ^ (sp & 7)) << 2)] = pk;
        }
    }
    __syncthreads();

    // ---- K-loop: 9 uniform (kd,kh); inner 3 kw x 4 cc; 2 tiles share A ----
    const int wp    = lane & 31;
    const int khalf = lane >> 5;
    const _Float16* wbase = wT + (lane & 31) * 64 + khalf * 8;

    floatx16 acc0 = {}, acc1 = {};
    #pragma unroll 1
    for (int t9 = 0; t9 < 9; ++t9) {
        const int kd = t9 / 3, kh = t9 - 3 * kd;
        const int r0 = (2 - kd) * 10 + (2 * wv + 2 - kh);   // tile t row = r0 + t
        #pragma unroll
        for (int kw = 0; kw < 3; ++kw) {
            const int sp0 = r0 * 34 + (wp + 2 - kw);
            const int sp1 = sp0 + 34;
            const unsigned int* x0 = xlds + sp0 * 32;
            const unsigned int* x1 = xlds + sp1 * 32;
            const int s07 = sp0 & 7, s17 = sp1 & 7;
            const _Float16* wt = wbase + (t9 * 3 + kw) * 2048;
            #pragma unroll
            for (int cc = 0; cc < 4; ++cc) {
                const int g = cc * 2 + khalf;
                uint4 au = *(const uint4*)(wt + cc * 16);
                uint4 b0 = *(const uint4*)(x0 + ((g ^ s07) << 2));
                uint4 b1 = *(const uint4*)(x1 + ((g ^ s17) << 2));
                acc0 = __builtin_amdgcn_mfma_f32_32x32x16_f16(
                    __builtin_bit_cast(half8, au), __builtin_bit_cast(half8, b0),
                    acc0, 0, 0, 0);
                acc1 = __builtin_amdgcn_mfma_f32_32x32x16_f16(
                    __builtin_bit_cast(half8, au), __builtin_bit_cast(half8, b1),
                    acc1, 0, 0, 0);
            }
        }
    }

    // ---- stores: this block covers oh rows [16hpg, 16hpg+16) of plane od ----
    const int od = 2 * dp + 1;
    #pragma unroll
    for (int t = 0; t < 2; ++t) {
        const int hp = hpb + 2 * wv + t;
        const int oh_odd = 2 * hp + 1, oh_even = 2 * hp;
        const floatx16& acc = t ? acc1 : acc0;
        const bool tailrows = (hpg == 3) && (wv == 3) && (t == 1);
        #pragma unroll
        for (int r = 0; r < 16; ++r) {
            const int co = (r & 3) + 8 * (r >> 2) + 4 * khalf;   // verified C/D map
            const float bv = bias[co];
            float* pbase = out + ((size_t)(n * 32 + co) * DOUT + od) * PL;
            float2* orow = (float2*)(pbase + oh_odd * DOUT);
            float2* erow = (float2*)(pbase + oh_even * DOUT);
            orow[wp] = make_float2(bv, acc[r] + bv);
            erow[wp] = make_float2(bv, bv);
            if (wp == 31) {
                orow[32] = make_float2(bv, bv);
                erow[32] = make_float2(bv, bv);
            }
            if (tailrows) {                          // oh = 64, 65
                float2* t0 = (float2*)(pbase + 64 * DOUT);
                float2* t1 = (float2*)(pbase + 65 * DOUT);
                t0[wp] = make_float2(bv, bv);
                t1[wp] = make_float2(bv, bv);
                if (wp == 31) { t0[32] = make_float2(bv, bv); t1[32] = make_float2(bv, bv); }
            }
        }
    }
}

extern "C" void kernel_launch(void* const* d_in, const int* in_sizes, int n_in,
                              void* d_out, int out_size, void* d_ws, size_t ws_size,
                              hipStream_t stream) {
    const float* x    = (const float*)d_in[0];
    const float* wgt  = (const float*)d_in[1];
    const float* bias = (const float*)d_in[2];
    float* out = (float*)d_out;
    _Float16* wT = (_Float16*)d_ws;                  // 110,592 B scratch

    // allow >64 KB dynamic LDS (no-op if already set; safe under graph capture)
    static bool attr_done = false;
    if (!attr_done) {
        hipFuncSetAttribute((const void*)convt_mfma,
                            hipFuncAttributeMaxDynamicSharedMemorySize,
                            CONV_LDS_BYTES);
        attr_done = true;
    }

    w_transpose<<<216, 256, 0, stream>>>(wgt, wT);
    bias_planes<<<(BIAS_TOT4 + 4095) / 4096, 256, 0, stream>>>(bias, out);
    convt_mfma<<<256, 256, CONV_LDS_BYTES, stream>>>(x, wT, bias, out);
}